// Round 9
// baseline (152.186 us; speedup 1.0000x reference)
//
#include <hip/hip_runtime.h>
#include <hip/hip_bf16.h>
#include <stdint.h>

#define B_DIM 8192
#define I_DIM 1024
#define H_DIM 1024

typedef __attribute__((ext_vector_type(8))) short short8;
typedef __attribute__((ext_vector_type(4))) float f32x4;

static __device__ __forceinline__ short f2b(float f) {
    __bf16 h = (__bf16)f;
    return __builtin_bit_cast(short, h);
}

static __device__ __forceinline__ short8 pack8(float4 a, float4 b) {
    short8 s;
    s[0] = f2b(a.x); s[1] = f2b(a.y); s[2] = f2b(a.z); s[3] = f2b(a.w);
    s[4] = f2b(b.x); s[5] = f2b(b.y); s[6] = f2b(b.z); s[7] = f2b(b.w);
    return s;
}

static __device__ __forceinline__ float sigmoid_f(float x) {
    return 1.0f / (1.0f + __expf(-x));
}

static __device__ __forceinline__ float tanh_fast(float x) {
    x = fminf(fmaxf(x, -15.0f), 15.0f);
    float e = __expf(2.0f * x);
    return (e - 1.0f) / (e + 1.0f);
}

static __device__ __forceinline__ void load_lds16(const void* gptr, void* lptr) {
    __builtin_amdgcn_global_load_lds(
        (const __attribute__((address_space(1))) uint32_t*)gptr,
        (__attribute__((address_space(3))) uint32_t*)lptr, 16, 0, 0);
}

// ---------------------------------------------------------------------------
// Pass 1: fp32 -> bf16 conversion into FRAGMENT-ORDERED workspace (unchanged).
//   A_fw: [mfrag 0..511][k32 0..63][lane 0..63][8 bf16]
//         row = mfrag*16 + (lane&15), k = k32*32 + (lane>>4)*8
//   B_fw: [nfrag 0..255][k32][lane][8]
//         nfrag = bn*16 + cf; gate = cf&3; col = bn*64 + (cf>>2)*16 + (lane&15)
// ---------------------------------------------------------------------------
#define GA_GROUPS (512 * 32 * 2 * 64)   // 2,097,152  (A 16B-groups)
#define GB_GROUPS (256 * 32 * 2 * 64)   // 1,048,576  (B 16B-groups)

__global__ __launch_bounds__(256) void convert_kernel(
    const float* __restrict__ x, const float* __restrict__ h,
    const float* __restrict__ wx, const float* __restrict__ wh,
    short* __restrict__ Aw, short* __restrict__ Bw)
{
    const int64_t total = (int64_t)GA_GROUPS + GB_GROUPS;
    for (int64_t g = (int64_t)blockIdx.x * blockDim.x + threadIdx.x; g < total;
         g += (int64_t)gridDim.x * blockDim.x) {
        const float* src;
        short* dst;
        if (g < GA_GROUPS) {
            const int lane = (int)(g & 63);
            const int rest = (int)(g >> 6);
            const int kh   = rest & 1;
            const int tk   = (rest >> 1) & 31;
            const int mfrag = rest >> 6;
            const int row = (mfrag << 4) + (lane & 15);
            const int k   = (tk << 6) + (kh << 5) + ((lane >> 4) << 3);
            src = (k < 1024) ? (x + (size_t)row * 1024 + k)
                             : (h + (size_t)row * 1024 + (k - 1024));
            dst = Aw + (size_t)g * 8;
        } else {
            const int64_t gb = g - GA_GROUPS;
            const int lane = (int)(gb & 63);
            const int rest = (int)(gb >> 6);
            const int kh   = rest & 1;
            const int tk   = (rest >> 1) & 31;
            const int nfrag = rest >> 6;
            const int cf   = nfrag & 15;
            const int bn   = nfrag >> 4;
            const int gate = cf & 3;
            const int col  = (bn << 6) + ((cf >> 2) << 4) + (lane & 15);
            const int k    = (tk << 6) + (kh << 5) + ((lane >> 4) << 3);
            src = (k < 1024) ? (wx + ((size_t)(gate << 10) + col) * 1024 + k)
                             : (wh + ((size_t)(gate << 10) + col) * 1024 + (k - 1024));
            dst = Bw + (size_t)gb * 8;
        }
        float4 v0 = ((const float4*)src)[0];
        float4 v1 = ((const float4*)src)[1];
        *(short8*)dst = pack8(v0, v1);
    }
}

// ---------------------------------------------------------------------------
// Pass 2: 128x128-tile GEMM, BK=32, 4 waves/block, 32 KiB LDS -> 4 blocks/CU
// (same 16 waves/CU as round 8 but 4 INDEPENDENT barrier domains — quarters
// the blast radius of each barrier/vmcnt so pipes cross-fill).
// Per-wave 64x64 (4 gates x 16 h), acc 64 regs. One barrier + one vmcnt(0)
// per k32-tile. Fragment-ordered workspace, fragment-tile LDS (0 conflicts).
// Fused in-register LSTM epilogue.
// LDS: [2 dbuf][ A 8 frags | B 8 frags ][512 shorts] = 32 KiB.
// ---------------------------------------------------------------------------
#define AOFF(d, f) ((d) * 8192 + (f) * 512)
#define BOFF(d, f) ((d) * 8192 + 4096 + (f) * 512)

__global__ __launch_bounds__(256, 4) void lstm_gemm_tlp_kernel(
    const short* __restrict__ Aw, const short* __restrict__ Bw,
    const float* __restrict__ cprev, const float* __restrict__ bh,
    float* __restrict__ out)
{
    __shared__ __align__(16) short smem[16384];   // 32 KiB

    // XCD-aware: hw round-robins blockIdx -> XCD (xcd = bid&7). Each XCD works
    // h-tiles 4*xcd..4*xcd+3: its ~2 MB B-slice stays L2-resident; A streams.
    const int bid = blockIdx.x;
    const int xcd = bid & 7;
    const int c   = bid >> 3;            // 0..255 within XCD
    const int bm  = c >> 2;              // 0..63  (128-row M tile)
    const int ht  = 4 * xcd + (c & 3);   // 0..31  (32-h N tile)
    const int m0  = bm * 128;

    const int t    = threadIdx.x;
    const int lane = t & 63;
    const int w    = t >> 6;     // wave 0..3
    const int wm   = w >> 1;     // 0..1  M half
    const int wn   = w & 1;      // 0..1  N half (16-h group)
    const int lc   = lane & 15;

    // staging sources (contiguous 1 KiB per gload): wave w stages A-frags
    // 2w,2w+1 and B-frags 2w,2w+1. Frag stride = 64 k32-tiles * 512 shorts.
    const short* aSrc0 = Aw + (size_t)(bm * 8 + 2 * w)     * 32768 + lane * 8;
    const short* aSrc1 = Aw + (size_t)(bm * 8 + 2 * w + 1) * 32768 + lane * 8;
    const short* bSrc0 = Bw + (size_t)(ht * 8 + 2 * w)     * 32768 + lane * 8;
    const short* bSrc1 = Bw + (size_t)(ht * 8 + 2 * w + 1) * 32768 + lane * 8;

    f32x4 acc[4][4] = {};   // [m-frag][gate]

    // prologue: stage k32-tile 0 into dbuf 0
    load_lds16(aSrc0, &smem[AOFF(0, 2 * w)]);
    load_lds16(aSrc1, &smem[AOFF(0, 2 * w + 1)]);
    load_lds16(bSrc0, &smem[BOFF(0, 2 * w)]);
    load_lds16(bSrc1, &smem[BOFF(0, 2 * w + 1)]);
    asm volatile("s_waitcnt vmcnt(0)" ::: "memory");
    __builtin_amdgcn_s_barrier();

#define TILE(d, tp) do { \
    short8 bv[4], av[4]; \
    _Pragma("unroll") \
    for (int j = 0; j < 4; ++j) \
        bv[j] = *(const short8*)&smem[BOFF(d, wn * 4 + j) + lane * 8]; \
    _Pragma("unroll") \
    for (int i = 0; i < 4; ++i) \
        av[i] = *(const short8*)&smem[AOFF(d, wm * 4 + i) + lane * 8]; \
    load_lds16(aSrc0 + (tp) * 512, &smem[AOFF(d ^ 1, 2 * w)]); \
    load_lds16(aSrc1 + (tp) * 512, &smem[AOFF(d ^ 1, 2 * w + 1)]); \
    load_lds16(bSrc0 + (tp) * 512, &smem[BOFF(d ^ 1, 2 * w)]); \
    load_lds16(bSrc1 + (tp) * 512, &smem[BOFF(d ^ 1, 2 * w + 1)]); \
    __builtin_amdgcn_s_setprio(1); \
    _Pragma("unroll") \
    for (int i = 0; i < 4; ++i) \
        _Pragma("unroll") \
        for (int j = 0; j < 4; ++j) \
            acc[i][j] = __builtin_amdgcn_mfma_f32_16x16x32_bf16( \
                av[i], bv[j], acc[i][j], 0, 0, 0); \
    __builtin_amdgcn_s_setprio(0); \
    asm volatile("s_waitcnt vmcnt(0)" ::: "memory"); \
    __builtin_amdgcn_s_barrier(); \
} while (0)

    #pragma unroll 1
    for (int tk2 = 0; tk2 < 32; ++tk2) {
        const int t1 = 2 * tk2 + 1;
        const int t2 = (t1 + 1 < 64) ? t1 + 1 : t1;
        TILE(0, t1);
        TILE(1, t2);
    }
#undef TILE

    // ---- fused LSTM epilogue, in-register ----
    // D layout: col = lane&15 (h), row = (lane>>4)*4 + reg
    const int rg = lane >> 4;
    const int h  = ht * 32 + wn * 16 + lc;
    const float b_i = bh[0 * H_DIM + h];
    const float b_f = bh[1 * H_DIM + h];
    const float b_g = bh[2 * H_DIM + h];
    const float b_o = bh[3 * H_DIM + h];

    #pragma unroll
    for (int mf = 0; mf < 4; ++mf) {
        #pragma unroll
        for (int r = 0; r < 4; ++r) {
            const int row = m0 + wm * 64 + mf * 16 + rg * 4 + r;
            const float pi = acc[mf][0][r] + b_i;
            const float pf = acc[mf][1][r] + b_f;
            const float pg = acc[mf][2][r] + b_g;
            const float po = acc[mf][3][r] + b_o;
            const float iv = sigmoid_f(pi);
            const float fv = sigmoid_f(pf);
            const float gv = tanh_fast(pg);
            const float ov = sigmoid_f(po);
            const float cp = cprev[(size_t)row * H_DIM + h];
            const float cn = fv * cp + iv * gv;
            const float hn = ov * tanh_fast(cn);
            out[(size_t)row * H_DIM + h] = hn;
            out[(size_t)B_DIM * H_DIM + (size_t)row * H_DIM + h] = cn;
        }
    }
}

// ---------------------------------------------------------------------------
// Fallback (no workspace) — kept for safety.
// ---------------------------------------------------------------------------
static __device__ __forceinline__ int swz(int row, int k) {
    int byte = (row << 7) + (k << 1);
    byte ^= (row & 7) << 4;
    return byte >> 1;
}

__global__ __launch_bounds__(256, 2) void lstm_fallback_kernel(
    const float* __restrict__ x, const float* __restrict__ hprev,
    const float* __restrict__ cprev, const float* __restrict__ Wx,
    const float* __restrict__ Wh, const float* __restrict__ bh,
    float* __restrict__ out)
{
    __shared__ __align__(16) short As[128 * 64];
    __shared__ __align__(16) short Bs[128 * 64];

    int bid = blockIdx.x;
    bid = (bid & 7) * 256 + (bid >> 3);
    const int mt = bid >> 5;
    const int ht = bid & 31;
    const int m0 = mt * 128;
    const int h0 = ht * 32;

    const int t    = threadIdx.x;
    const int lane = t & 63;
    const int w    = t >> 6;
    const int wr   = w >> 1;
    const int wc   = w & 1;

    const int srow = t >> 3;
    const int sk   = (t & 7) * 8;

    f32x4 acc[4][4] = {};

    #pragma unroll 1
    for (int phase = 0; phase < 2; ++phase) {
        const float* __restrict__ Ap = phase ? hprev : x;
        const float* __restrict__ Bp = phase ? Wh : Wx;
        #pragma unroll 1
        for (int kk = 0; kk < 1024; kk += 64) {
            __syncthreads();
            #pragma unroll
            for (int p = 0; p < 4; ++p) {
                const int row = srow + p * 32;
                const float4* src = (const float4*)(Ap + (size_t)(m0 + row) * I_DIM + kk + sk);
                *(short8*)&As[swz(row, sk)] = pack8(src[0], src[1]);
            }
            #pragma unroll
            for (int p = 0; p < 4; ++p) {
                const int n    = srow + p * 32;
                const int gate = (n >> 4) & 3;
                const int hcol = h0 + ((n >> 6) << 4) + (n & 15);
                const float4* src = (const float4*)(Bp + (size_t)((gate << 10) + hcol) * 1024 + kk + sk);
                *(short8*)&Bs[swz(n, sk)] = pack8(src[0], src[1]);
            }
            __syncthreads();
            #pragma unroll
            for (int ks = 0; ks < 2; ++ks) {
                const int kb = ks * 32 + ((lane >> 4) << 3);
                short8 a[4], b[4];
                #pragma unroll
                for (int m = 0; m < 4; ++m)
                    a[m] = *(const short8*)&As[swz(wr * 64 + m * 16 + (lane & 15), kb)];
                #pragma unroll
                for (int j = 0; j < 4; ++j)
                    b[j] = *(const short8*)&Bs[swz(wc * 64 + j * 16 + (lane & 15), kb)];
                #pragma unroll
                for (int m = 0; m < 4; ++m)
                    #pragma unroll
                    for (int j = 0; j < 4; ++j)
                        acc[m][j] = __builtin_amdgcn_mfma_f32_16x16x32_bf16(a[m], b[j], acc[m][j], 0, 0, 0);
            }
        }
    }

    const int cl = lane & 15;
    const int rg = lane >> 4;
    const int h  = h0 + wc * 16 + cl;
    const float b_i = bh[0 * H_DIM + h];
    const float b_f = bh[1 * H_DIM + h];
    const float b_g = bh[2 * H_DIM + h];
    const float b_o = bh[3 * H_DIM + h];

    #pragma unroll
    for (int m = 0; m < 4; ++m) {
        #pragma unroll
        for (int r = 0; r < 4; ++r) {
            const int row = m0 + wr * 64 + m * 16 + rg * 4 + r;
            const float pi = acc[m][0][r] + b_i;
            const float pf = acc[m][1][r] + b_f;
            const float pg = acc[m][2][r] + b_g;
            const float po = acc[m][3][r] + b_o;
            const float iv = sigmoid_f(pi);
            const float fv = sigmoid_f(pf);
            const float gv = tanh_fast(pg);
            const float ov = sigmoid_f(po);
            const float cp = cprev[(size_t)row * H_DIM + h];
            const float cn = fv * cp + iv * gv;
            const float hn = ov * tanh_fast(cn);
            out[(size_t)row * H_DIM + h] = hn;
            out[(size_t)B_DIM * H_DIM + (size_t)row * H_DIM + h] = cn;
        }
    }
}

extern "C" void kernel_launch(void* const* d_in, const int* in_sizes, int n_in,
                              void* d_out, int out_size, void* d_ws, size_t ws_size,
                              hipStream_t stream) {
    const float* x     = (const float*)d_in[0];
    const float* hprev = (const float*)d_in[1];
    const float* cprev = (const float*)d_in[2];
    const float* Wx    = (const float*)d_in[3];
    const float* Wh    = (const float*)d_in[4];
    const float* bh    = (const float*)d_in[5];
    float* out = (float*)d_out;

    const size_t need = ((size_t)B_DIM * 2048 + (size_t)4096 * 2048) * sizeof(short);
    if (ws_size >= need && d_ws != nullptr) {
        short* Aw = (short*)d_ws;                 // A_fw: 512 frags * 32768 shorts
        short* Bw = Aw + (size_t)512 * 32768;     // B_fw: 256 frags * 32768 shorts
        hipLaunchKernelGGL(convert_kernel, dim3(4096), dim3(256), 0, stream,
                           x, hprev, Wx, Wh, Aw, Bw);
        hipLaunchKernelGGL(lstm_gemm_tlp_kernel, dim3(2048), dim3(256), 0, stream,
                           Aw, Bw, cprev, bh, out);
    } else {
        hipLaunchKernelGGL(lstm_fallback_kernel, dim3(2048), dim3(256), 0, stream,
                           x, hprev, cprev, Wx, Wh, bh, out);
    }
}